// Round 1
// baseline (1621.161 us; speedup 1.0000x reference)
//
#include <hip/hip_runtime.h>

// Problem constants
#define BATCH 256
#define TT 1024
#define IN_DIM 96
#define NU 256
#define NC 10
#define EPS 0.01f
#define BETA 0.5f
#define GAMMA 0.0f

typedef _Float16 f16x8 __attribute__((ext_vector_type(8)));
typedef float f32x4 __attribute__((ext_vector_type(4)));

// workspace layout (bytes)
#define ZP_BYTES ((size_t)TT * BATCH * NU * 2)     // 134,217,728  z' f16 [t][b][n]
#define WSW_OFF  ZP_BYTES
#define WSW_BYTES ((size_t)8 * 8 * 4 * 64 * 8 * 2) // 262,144  W frags f16 (x16 scaled)
#define ESW_OFF  (WSW_OFF + WSW_BYTES)
#define ESW_BYTES ((size_t)4 * 3 * 4 * 64 * 8 * 2) // 49,152  E frags f16

// ---------------------------------------------------------------------------
// prep_w: build W = [Dm | A] (K=256 x N=512) as pre-swizzled B-operand frags.
// B-frag layout (16x16x32): lane l holds B[k = (l>>4)*8 + j][n = l&15], j=0..7.
// Wsw flat layout: [wave w<8][chunk c<8][tile i<4][lane l<64][8 halfs]
// Values scaled x16 (paired with h/16 storage) to keep f16 in range.
__global__ void prep_w(const float* __restrict__ C, const float* __restrict__ B,
                       _Float16* __restrict__ Wsw) {
    int u = blockIdx.x * 256 + threadIdx.x;   // 16384 units
    int l = u & 63;
    int i = (u >> 6) & 3;
    int c = (u >> 8) & 7;
    int w = u >> 11;
    int n = w * 64 + i * 16 + (l & 15);       // 0..511
    int kb = c * 32 + (l >> 4) * 8;
    const float* M = (n >= 256) ? C : B;      // n<256: Dm from B; n>=256: A from C
    int nn = (n >= 256) ? (n - 256) : n;
    f16x8 v;
#pragma unroll
    for (int j = 0; j < 8; j++) {
        int k = kb + j;
        float m1 = M[k * NU + nn];
        float m2 = M[nn * NU + k];
        float val = BETA * (m1 - m2) + (1.0f - BETA) * (m1 + m2)
                    - ((k == nn) ? GAMMA : 0.0f);
        v[j] = (_Float16)(val * 16.0f);
    }
    ((f16x8*)Wsw)[u] = v;
}

// ---------------------------------------------------------------------------
// prep_e: E_w [256][96] -> B-operand frags for z = x @ E_w^T  (K=96, N=256).
// Esw flat: [wave w<4][chunk c<3][tile i<4][lane l<64][8 halfs]. Unscaled.
__global__ void prep_e(const float* __restrict__ Ew, _Float16* __restrict__ Esw) {
    int u = blockIdx.x * 256 + threadIdx.x;   // 3072 units
    int l = u & 63;
    int i = (u >> 6) & 3;
    int wc = u >> 8;                          // 0..11 = w*3+c
    int c = wc % 3;
    int w = wc / 3;
    int n = w * 64 + i * 16 + (l & 15);
    int kb = c * 32 + (l >> 4) * 8;
    f16x8 v;
#pragma unroll
    for (int j = 0; j < 8; j++)
        v[j] = (_Float16)Ew[n * IN_DIM + kb + j];
    ((f16x8*)Esw)[u] = v;
}

// ---------------------------------------------------------------------------
// zproj: z'[t][b][n] = (f16)(x[b][t][:] @ E_w^T + E_b)  via MFMA.
// Block = 256 thr (4 waves), handles 64 bt-rows; wave w owns cols w*64..+63.
__global__ __launch_bounds__(256) void zproj(const float* __restrict__ x,
                                             const float* __restrict__ Eb,
                                             const _Float16* __restrict__ Esw,
                                             _Float16* __restrict__ zp) {
    __shared__ __align__(16) _Float16 xh[64 * 104];  // x rows as f16, pad 96->104
    __shared__ float eb[NU];
    int tid = threadIdx.x;
    int l = tid & 63, w = tid >> 6, m = l & 15, quad = l >> 4;
    size_t R0 = (size_t)blockIdx.x * 64;

    const float* xb = x + R0 * IN_DIM;
#pragma unroll
    for (int it = 0; it < 24; it++) {         // 64*96/256 = 24 per thread
        int idx = tid + it * 256;
        int r = idx / 96, k = idx - r * 96;
        xh[r * 104 + k] = (_Float16)xb[idx];
    }
    eb[tid] = Eb[tid];

    f16x8 ef[3][4];
    const f16x8* Ep = (const f16x8*)Esw;
#pragma unroll
    for (int c = 0; c < 3; c++)
#pragma unroll
        for (int i = 0; i < 4; i++)
            ef[c][i] = Ep[((w * 3 + c) * 4 + i) * 64 + l];
    __syncthreads();

    f32x4 zero4 = {0.f, 0.f, 0.f, 0.f};
    f32x4 acc[4][4];
#pragma unroll
    for (int mt = 0; mt < 4; mt++)
#pragma unroll
        for (int i = 0; i < 4; i++) acc[mt][i] = zero4;

#pragma unroll
    for (int mt = 0; mt < 4; mt++) {
#pragma unroll
        for (int c = 0; c < 3; c++) {
            f16x8 af = *(const f16x8*)&xh[(mt * 16 + m) * 104 + c * 32 + quad * 8];
#pragma unroll
            for (int i = 0; i < 4; i++)
                acc[mt][i] = __builtin_amdgcn_mfma_f32_16x16x32_f16(af, ef[c][i],
                                                                    acc[mt][i], 0, 0, 0);
        }
    }

#pragma unroll
    for (int mt = 0; mt < 4; mt++)
#pragma unroll
        for (int i = 0; i < 4; i++) {
            int col = w * 64 + i * 16 + m;
            float ebv = eb[col];
#pragma unroll
            for (int r = 0; r < 4; r++) {
                size_t gr = R0 + (size_t)(mt * 16 + quad * 4 + r);
                size_t b = gr >> 10, t = gr & 1023;
                zp[(t * BATCH + b) * NU + col] = (_Float16)(acc[mt][i][r] + ebv);
            }
        }
}

// ---------------------------------------------------------------------------
// Recurrence: 16 WGs x 512 thr (8 waves). WG owns 16 batch rows.
// Weights resident in VGPRs (wave w owns cols w*64..+63 of [Dm|A], 128 VGPRs).
// Per step: MFMA [16x256]@[256x512] -> Y (LDS) -> h update (fp32 regs) -> h/16
// republished to LDS as f16 A-frags. z prefetched 2 steps deep into registers.
__device__ __forceinline__ void step_fn(_Float16* hl, float* Y,
                                        const f16x8 wf[8][4], float hreg[8],
                                        f16x8& zcur, const f16x8* zv,
                                        size_t zbase, int tnext,
                                        int m, int quad, int w, int hr, int c0) {
    f32x4 facc[4];
    f32x4 zero4 = {0.f, 0.f, 0.f, 0.f};
#pragma unroll
    for (int i = 0; i < 4; i++) facc[i] = zero4;
#pragma unroll
    for (int c = 0; c < 8; c++) {
        f16x8 af = *(const f16x8*)&hl[m * 264 + c * 32 + quad * 8];
#pragma unroll
        for (int i = 0; i < 4; i++)
            facc[i] = __builtin_amdgcn_mfma_f32_16x16x32_f16(af, wf[c][i], facc[i], 0, 0, 0);
    }
#pragma unroll
    for (int i = 0; i < 4; i++) {
        int col = w * 64 + i * 16 + m;
#pragma unroll
        for (int r = 0; r < 4; r++)
            Y[(quad * 4 + r) * 516 + col] = facc[i][r];
    }
    __syncthreads();

    float zf[8];
#pragma unroll
    for (int e = 0; e < 8; e++) zf[e] = (float)zcur[e];
    zcur = zv[zbase + (size_t)tnext * 8192];   // prefetch z[tnext]

    f32x4 d0 = *(const f32x4*)&Y[hr * 516 + c0];
    f32x4 d1 = *(const f32x4*)&Y[hr * 516 + c0 + 4];
    f32x4 a0 = *(const f32x4*)&Y[hr * 516 + 256 + c0];
    f32x4 a1 = *(const f32x4*)&Y[hr * 516 + 256 + c0 + 4];
    float yD[8] = {d0[0], d0[1], d0[2], d0[3], d1[0], d1[1], d1[2], d1[3]};
    float yA[8] = {a0[0], a0[1], a0[2], a0[3], a1[0], a1[1], a1[2], a1[3]};

    f16x8 hv;
#pragma unroll
    for (int e = 0; e < 8; e++) {
        float xin = yA[e] + zf[e];
        float ex = __expf(2.0f * xin);         // overflow-safe tanh
        float th = 1.0f - 2.0f / (ex + 1.0f);
        hreg[e] += EPS * yD[e] + EPS * th;
        hv[e] = (_Float16)(hreg[e] * 0.0625f); // store h/16 (pairs with W*16)
    }
    *(f16x8*)&hl[hr * 264 + c0] = hv;
    __syncthreads();
}

__global__ __launch_bounds__(512, 2) void recur(const _Float16* __restrict__ Wsw,
                                                const _Float16* __restrict__ zp,
                                                const float* __restrict__ Dw,
                                                const float* __restrict__ Db,
                                                float* __restrict__ out) {
    __shared__ __align__(16) _Float16 hl[16 * 264];  // h/16 f16, pad 256->264
    __shared__ __align__(16) float Y[16 * 516];      // [16][512] + pad 4
    int tid = threadIdx.x;
    int l = tid & 63, w = tid >> 6, m = l & 15, quad = l >> 4;
    int r0 = blockIdx.x * 16;

    f16x8 wf[8][4];
    const f16x8* Wp = (const f16x8*)Wsw;
#pragma unroll
    for (int c = 0; c < 8; c++)
#pragma unroll
        for (int i = 0; i < 4; i++)
            wf[c][i] = Wp[((w * 8 + c) * 4 + i) * 64 + l];

    int hr = tid >> 5, c0 = (tid & 31) * 8;   // thread owns h[hr][c0..c0+7]
    float hreg[8];
#pragma unroll
    for (int e = 0; e < 8; e++) hreg[e] = 0.0f;

    for (int idx = tid; idx < 16 * 264; idx += 512) hl[idx] = (_Float16)0.0f;

    const f16x8* zv = (const f16x8*)zp;
    size_t zbase = (size_t)(r0 + hr) * 32 + (c0 >> 3);
    f16x8 za = zv[zbase];                      // z[0]
    f16x8 zb = zv[zbase + 8192];               // z[1]
    __syncthreads();

    for (int t = 0; t < TT; t += 2) {
        int t2 = (t + 2 > TT - 1) ? TT - 1 : t + 2;
        int t3 = (t + 3 > TT - 1) ? TT - 1 : t + 3;
        step_fn(hl, Y, wf, hreg, za, zv, zbase, t2, m, quad, w, hr, c0);
        step_fn(hl, Y, wf, hreg, zb, zv, zbase, t3, m, quad, w, hr, c0);
    }

    // epilogue: out[b][c] = h[b][:] @ Dw[c][:] + Db[c]
#pragma unroll
    for (int e = 0; e < 8; e++) Y[hr * 260 + c0 + e] = hreg[e];
    __syncthreads();
    if (tid < 160) {
        int rr = tid / 10, c = tid - rr * 10;
        float s = Db[c];
        for (int k = 0; k < 256; k++) s += Y[rr * 260 + k] * Dw[c * 256 + k];
        out[(r0 + rr) * 10 + c] = s;
    }
}

// ---------------------------------------------------------------------------
extern "C" void kernel_launch(void* const* d_in, const int* in_sizes, int n_in,
                              void* d_out, int out_size, void* d_ws, size_t ws_size,
                              hipStream_t stream) {
    const float* x  = (const float*)d_in[0];
    const float* Ew = (const float*)d_in[1];
    const float* Eb = (const float*)d_in[2];
    const float* C  = (const float*)d_in[3];
    const float* B  = (const float*)d_in[4];
    const float* Dw = (const float*)d_in[5];
    const float* Db = (const float*)d_in[6];
    float* out = (float*)d_out;

    char* ws = (char*)d_ws;
    _Float16* zp  = (_Float16*)(ws);
    _Float16* Wsw = (_Float16*)(ws + WSW_OFF);
    _Float16* Esw = (_Float16*)(ws + ESW_OFF);

    hipLaunchKernelGGL(prep_w, dim3(64), dim3(256), 0, stream, C, B, Wsw);
    hipLaunchKernelGGL(prep_e, dim3(12), dim3(256), 0, stream, Ew, Esw);
    hipLaunchKernelGGL(zproj, dim3(4096), dim3(256), 0, stream, x, Eb, Esw, zp);
    hipLaunchKernelGGL(recur, dim3(16), dim3(512), 0, stream, Wsw, zp, Dw, Db, out);
}